// Round 1
// baseline (193.619 us; speedup 1.0000x reference)
//
#include <hip/hip_runtime.h>
#include <math.h>

// Problem geometry (fixed): B=8, C=4, H=W=256; 24 = B*3 slices per mask type.
#define HWTOT 65536
#define WD 256
#define HT 256
#define NSL 24

// Workspace layout (bytes)
static constexpr size_t OFF_CNT   = 0;                       // 48 ints (pred: 0..23, tgt: 24..47)
static constexpr size_t OFF_PART  = 256;                     // 6144 f32 partials
static constexpr size_t HDR_BYTES = 256 + 6144 * 4;          // 24832, memset region
static constexpr size_t OFF_MASKP = 24832;
static constexpr size_t OFF_MASKT = OFF_MASKP + (size_t)NSL * HWTOT;       // 1597696
static constexpr size_t OFF_GP    = OFF_MASKT + (size_t)NSL * HWTOT;       // 3170560
static constexpr size_t OFF_GPC   = OFF_GP  + (size_t)NSL * HWTOT * 2;     // 6316288
static constexpr size_t OFF_GT    = OFF_GPC + (size_t)NSL * HWTOT * 2;     // 9462016
static constexpr size_t OFF_GTC   = OFF_GT  + (size_t)NSL * HWTOT * 2;     // 12607744

// ---------------- Kernel 1: masks + per-slice counts ----------------
__global__ __launch_bounds__(256) void k_mask(
    const float* __restrict__ pS, const float* __restrict__ pT,
    unsigned char* __restrict__ maskP, unsigned char* __restrict__ maskT,
    int* __restrict__ cnts)
{
    __shared__ int lc[6];
    if (threadIdx.x < 6) lc[threadIdx.x] = 0;
    __syncthreads();

    int t  = blockIdx.x * 256 + threadIdx.x;   // 0 .. 524287
    int b  = t >> 16;
    int hw = t & (HWTOT - 1);

    const float* ps = pS + (size_t)b * 4 * HWTOT + hw;
    float s0 = ps[0], s1 = ps[HWTOT], s2 = ps[2 * HWTOT], s3 = ps[3 * HWTOT];
    float mx = fmaxf(fmaxf(s0, s1), fmaxf(s2, s3));
    float e0 = expf(s0 - mx), e1 = expf(s1 - mx), e2 = expf(s2 - mx), e3 = expf(s3 - mx);
    float inv = 1.0f / (e0 + e1 + e2 + e3);

    const float* pt = pT + (size_t)b * 4 * HWTOT + hw;
    float t0 = pt[0], t1 = pt[HWTOT], t2 = pt[2 * HWTOT], t3 = pt[3 * HWTOT];
    int lab = 0; float bm = t0;
    if (t1 > bm) { bm = t1; lab = 1; }
    if (t2 > bm) { bm = t2; lab = 2; }
    if (t3 > bm) { bm = t3; lab = 3; }

    float pv[3] = { e1 * inv, e2 * inv, e3 * inv };
    #pragma unroll
    for (int cc = 0; cc < 3; ++cc) {
        int sl = b * 3 + cc;
        bool mp = pv[cc] > 0.5f;
        bool mt = (lab == cc + 1);
        maskP[(size_t)sl * HWTOT + hw] = mp ? 1 : 0;
        maskT[(size_t)sl * HWTOT + hw] = mt ? 1 : 0;
        unsigned long long balP = __ballot(mp);
        unsigned long long balT = __ballot(mt);
        if ((threadIdx.x & 63) == 0) {
            atomicAdd(&lc[cc],     (int)__popcll(balP));
            atomicAdd(&lc[3 + cc], (int)__popcll(balT));
        }
    }
    __syncthreads();
    if (threadIdx.x < 3) {
        atomicAdd(&cnts[b * 3 + threadIdx.x], lc[threadIdx.x]);
    } else if (threadIdx.x < 6) {
        atomicAdd(&cnts[24 + b * 3 + (threadIdx.x - 3)], lc[threadIdx.x]);
    }
}

// ---------------- Kernel 2: vertical 1D pass (both polarities) ----------------
// Matches the reference scan: g = min(g0, prev+1), g0 = mask ? INF(=512) : 0,
// forward then backward. One thread per (slice, column); blockIdx.y picks P/T.
__global__ __launch_bounds__(256) void k_vert(
    const unsigned char* __restrict__ maskP, const unsigned char* __restrict__ maskT,
    unsigned short* __restrict__ gP, unsigned short* __restrict__ gPc,
    unsigned short* __restrict__ gT, unsigned short* __restrict__ gTc)
{
    int s   = blockIdx.x;       // slice 0..23
    int typ = blockIdx.y;       // 0 = pred masks, 1 = tgt masks
    int w   = threadIdx.x;

    const unsigned char* m = (typ == 0 ? maskP : maskT) + (size_t)s * HWTOT;
    unsigned short* ga = (typ == 0 ? gP  : gT)  + (size_t)s * HWTOT;
    unsigned short* gb = (typ == 0 ? gPc : gTc) + (size_t)s * HWTOT;

    int prev = 512, prevC = 512;
    for (int h = 0; h < HT; ++h) {
        int idx = h * WD + w;
        int mm = m[idx];
        int gv  = mm ? min(prev  + 1, 512) : 0;
        int gcv = mm ? 0 : min(prevC + 1, 512);
        ga[idx] = (unsigned short)gv;
        gb[idx] = (unsigned short)gcv;
        prev = gv; prevC = gcv;
    }
    prev = 512; prevC = 512;
    for (int h = HT - 1; h >= 0; --h) {
        int idx = h * WD + w;
        int gv  = min((int)ga[idx], prev  + 1);
        int gcv = min((int)gb[idx], prevC + 1);
        ga[idx] = (unsigned short)gv;
        gb[idx] = (unsigned short)gcv;
        prev = gv; prevC = gcv;
    }
}

// ---------------- Kernel 3: horizontal exact min + fused loss ----------------
// Block = one (slice, row). dist2[jo] = min_j (g[j]^2 + (jo-j)^2), 4 fields at
// once via float4 LDS broadcast reads. Fused with err recompute + block reduce.
__global__ __launch_bounds__(256) void k_row(
    const float* __restrict__ pS, const float* __restrict__ pT,
    const unsigned short* __restrict__ gP, const unsigned short* __restrict__ gPc,
    const unsigned short* __restrict__ gT, const unsigned short* __restrict__ gTc,
    const int* __restrict__ cnts, float* __restrict__ partials)
{
    int h  = blockIdx.x;        // row 0..255
    int s  = blockIdx.y;        // slice 0..23 (= b*3 + cc)
    int b  = s / 3;
    int cc = s - b * 3;
    int jo = threadIdx.x;

    __shared__ float4 g2[WD];
    __shared__ float  red[256];

    size_t rbase = (size_t)s * HWTOT + h * WD + jo;
    {
        float a = (float)gP [rbase];
        float c = (float)gPc[rbase];
        float d = (float)gT [rbase];
        float e = (float)gTc[rbase];
        g2[jo] = make_float4(a * a, c * c, d * d, e * e);
    }
    __syncthreads();

    float m1 = 1e30f, m2 = 1e30f, m3 = 1e30f, m4 = 1e30f;
    float dj = (float)jo;
    #pragma unroll 8
    for (int j = 0; j < WD; ++j) {
        float4 g = g2[j];
        float d2 = dj * dj;
        m1 = fminf(m1, g.x + d2);
        m2 = fminf(m2, g.y + d2);
        m3 = fminf(m3, g.z + d2);
        m4 = fminf(m4, g.w + d2);
        dj -= 1.0f;
    }

    int cp = cnts[s];
    int ct = cnts[24 + s];
    float dtP = (cp > 0 && cp < HWTOT) ? (m1 + m2) : 0.0f;
    float dtT = (ct > 0 && ct < HWTOT) ? (m3 + m4) : 0.0f;

    // err = (p_c - onehot_c)^2, recomputed from inputs (coalesced row loads)
    size_t pix = (size_t)b * 4 * HWTOT + h * WD + jo;
    float s0 = pS[pix], s1 = pS[pix + HWTOT], s2 = pS[pix + 2 * HWTOT], s3 = pS[pix + 3 * HWTOT];
    float mx = fmaxf(fmaxf(s0, s1), fmaxf(s2, s3));
    float e0 = expf(s0 - mx), e1 = expf(s1 - mx), e2 = expf(s2 - mx), e3 = expf(s3 - mx);
    float inv = 1.0f / (e0 + e1 + e2 + e3);
    float pc = (cc == 0 ? e1 : (cc == 1 ? e2 : e3)) * inv;

    float t0 = pT[pix], t1 = pT[pix + HWTOT], t2 = pT[pix + 2 * HWTOT], t3 = pT[pix + 3 * HWTOT];
    int lab = 0; float bmv = t0;
    if (t1 > bmv) { bmv = t1; lab = 1; }
    if (t2 > bmv) { bmv = t2; lab = 2; }
    if (t3 > bmv) { bmv = t3; lab = 3; }
    float tc = (lab == cc + 1) ? 1.0f : 0.0f;

    float errv = (pc - tc) * (pc - tc);
    float contrib = errv * (dtP + dtT);

    red[jo] = contrib;
    __syncthreads();
    for (int off = 128; off > 0; off >>= 1) {
        if (jo < off) red[jo] += red[jo + off];
        __syncthreads();
    }
    if (jo == 0) partials[s * 256 + h] = red[0];
}

// ---------------- Kernel 4: final reduce (double) + log ----------------
__global__ __launch_bounds__(256) void k_final(
    const float* __restrict__ partials, float* __restrict__ out)
{
    __shared__ double red[256];
    int t = threadIdx.x;
    double acc = 0.0;
    for (int i = t; i < NSL * 256; i += 256) acc += (double)partials[i];
    red[t] = acc;
    __syncthreads();
    for (int off = 128; off > 0; off >>= 1) {
        if (t < off) red[t] += red[t + off];
        __syncthreads();
    }
    if (t == 0) {
        double loss = red[0] / (double)((size_t)NSL * HWTOT);
        out[0] = (float)log(loss + 1.0);
    }
}

extern "C" void kernel_launch(void* const* d_in, const int* in_sizes, int n_in,
                              void* d_out, int out_size, void* d_ws, size_t ws_size,
                              hipStream_t stream)
{
    const float* pS = (const float*)d_in[0];
    const float* pT = (const float*)d_in[1];
    // d_in[2] (target) is unused by the reference.
    float* out = (float*)d_out;

    char* ws = (char*)d_ws;
    int*            cnts   = (int*)(ws + OFF_CNT);
    float*          parts  = (float*)(ws + OFF_PART);
    unsigned char*  maskP  = (unsigned char*)(ws + OFF_MASKP);
    unsigned char*  maskT  = (unsigned char*)(ws + OFF_MASKT);
    unsigned short* gP     = (unsigned short*)(ws + OFF_GP);
    unsigned short* gPc    = (unsigned short*)(ws + OFF_GPC);
    unsigned short* gT     = (unsigned short*)(ws + OFF_GT);
    unsigned short* gTc    = (unsigned short*)(ws + OFF_GTC);

    hipMemsetAsync(ws, 0, HDR_BYTES, stream);

    k_mask <<<dim3(2048),      dim3(256), 0, stream>>>(pS, pT, maskP, maskT, cnts);
    k_vert <<<dim3(NSL, 2),    dim3(256), 0, stream>>>(maskP, maskT, gP, gPc, gT, gTc);
    k_row  <<<dim3(256, NSL),  dim3(256), 0, stream>>>(pS, pT, gP, gPc, gT, gTc, cnts, parts);
    k_final<<<dim3(1),         dim3(256), 0, stream>>>(parts, out);
}

// Round 2
// 130.164 us; speedup vs baseline: 1.4875x; 1.4875x over previous
//
#include <hip/hip_runtime.h>
#include <math.h>

// Problem geometry (fixed): B=8, C=4, H=W=256; 24 = B*3 slices per mask type.
#define HWTOT 65536
#define WD 256
#define HT 256
#define NSL 24

// Workspace layout (bytes)
static constexpr size_t OFF_CNT   = 0;                        // 48 ints (pred 0..23, tgt 24..47)
static constexpr size_t OFF_PART  = 256;                      // 6144 f32 partials
static constexpr size_t HDR_BYTES = 256 + 6144 * 4;           // 24832 (memset region)
static constexpr size_t OFF_MASK  = 24832;                    // 24*65536 u8 (bit0=P, bit1=T)
static constexpr size_t OFF_ERR   = OFF_MASK + (size_t)NSL * HWTOT;        // f16, 24*65536*2
static constexpr size_t OFF_G     = OFF_ERR + (size_t)NSL * HWTOT * 2;     // u16 x 4 fields
// fields: 0 = P (EDT of maskP), 1 = Pc, 2 = T, 3 = Tc; stride NSL*HWTOT u16 each

// ---------------- Kernel 1: masks + err + per-slice counts ----------------
__global__ __launch_bounds__(256) void k_mask(
    const float* __restrict__ pS, const float* __restrict__ pT,
    unsigned char* __restrict__ mask, _Float16* __restrict__ err,
    int* __restrict__ cnts)
{
    __shared__ int lc[6];
    if (threadIdx.x < 6) lc[threadIdx.x] = 0;
    __syncthreads();

    int t  = blockIdx.x * 256 + threadIdx.x;   // 0 .. 524287
    int b  = t >> 16;
    int hw = t & (HWTOT - 1);

    const float* ps = pS + (size_t)b * 4 * HWTOT + hw;
    float s0 = ps[0], s1 = ps[HWTOT], s2 = ps[2 * HWTOT], s3 = ps[3 * HWTOT];
    float mx = fmaxf(fmaxf(s0, s1), fmaxf(s2, s3));
    float e0 = expf(s0 - mx), e1 = expf(s1 - mx), e2 = expf(s2 - mx), e3 = expf(s3 - mx);
    float inv = 1.0f / (e0 + e1 + e2 + e3);

    const float* pt = pT + (size_t)b * 4 * HWTOT + hw;
    float t0 = pt[0], t1 = pt[HWTOT], t2 = pt[2 * HWTOT], t3 = pt[3 * HWTOT];
    int lab = 0; float bm = t0;
    if (t1 > bm) { bm = t1; lab = 1; }
    if (t2 > bm) { bm = t2; lab = 2; }
    if (t3 > bm) { bm = t3; lab = 3; }

    float pv[3] = { e1 * inv, e2 * inv, e3 * inv };
    #pragma unroll
    for (int cc = 0; cc < 3; ++cc) {
        int sl = b * 3 + cc;
        bool mp = pv[cc] > 0.5f;
        bool mt = (lab == cc + 1);
        mask[(size_t)sl * HWTOT + hw] = (unsigned char)((mp ? 1 : 0) | (mt ? 2 : 0));
        float tcv = mt ? 1.0f : 0.0f;
        float ev = (pv[cc] - tcv) * (pv[cc] - tcv);
        err[(size_t)sl * HWTOT + hw] = (_Float16)ev;
        unsigned long long balP = __ballot(mp);
        unsigned long long balT = __ballot(mt);
        if ((threadIdx.x & 63) == 0) {
            atomicAdd(&lc[cc],     (int)__popcll(balP));
            atomicAdd(&lc[3 + cc], (int)__popcll(balT));
        }
    }
    __syncthreads();
    if (threadIdx.x < 3) {
        atomicAdd(&cnts[b * 3 + threadIdx.x], lc[threadIdx.x]);
    } else if (threadIdx.x < 6) {
        atomicAdd(&cnts[24 + b * 3 + (threadIdx.x - 3)], lc[threadIdx.x]);
    }
}

// ---------------- Kernel 2: vertical 1D pass, column in registers ----------------
// Block = (slice s, field f). Thread = column. Forward scan packs g into 128
// VGPRs (2 x u16), backward scan runs entirely from registers, one store/row.
__global__ __launch_bounds__(256) void k_vert(
    const unsigned char* __restrict__ mask, unsigned short* __restrict__ g)
{
    int s = blockIdx.x;          // slice 0..23
    int f = blockIdx.y;          // field 0..3
    int w = threadIdx.x;
    int bit = f >> 1;            // 0 = pred mask, 1 = tgt mask
    int pol = f & 1;             // 0 = EDT(mask): free where bit==0; 1 = EDT(~mask)

    const unsigned char* m = mask + (size_t)s * HWTOT + w;
    unsigned short* go = g + ((size_t)f * NSL + s) * HWTOT + w;

    unsigned gp[128];
    int prev = 512;
    #pragma unroll
    for (int hb = 0; hb < 16; ++hb) {
        unsigned char mb[16];
        #pragma unroll
        for (int i = 0; i < 16; ++i) mb[i] = m[(hb * 16 + i) * WD];
        #pragma unroll
        for (int i = 0; i < 16; ++i) {
            int h = hb * 16 + i;
            int mv = (mb[i] >> bit) & 1;
            int gv = (mv == pol) ? 0 : min(prev + 1, 512);
            prev = gv;
            if ((h & 1) == 0) gp[h >> 1] = (unsigned)gv;
            else              gp[h >> 1] |= (unsigned)gv << 16;
        }
    }
    prev = 512;
    #pragma unroll
    for (int hb = 15; hb >= 0; --hb) {
        unsigned short outv[16];
        #pragma unroll
        for (int i = 15; i >= 0; --i) {
            int h = hb * 16 + i;
            unsigned pk = gp[h >> 1];
            int gf = (h & 1) ? (int)(pk >> 16) : (int)(pk & 0xffffu);
            int gv = min(gf, prev + 1);
            prev = gv;
            outv[i] = (unsigned short)gv;
        }
        #pragma unroll
        for (int i = 0; i < 16; ++i) go[(hb * 16 + i) * WD] = outv[i];
    }
}

// ---------------- Kernel 3: horizontal min, radius-limited, fused loss ----------------
// dist(jo) <= g_sel(jo), so only |jo-j| < g_sel can beat the init m = g_sel^2.
// Wave-uniform bound R = wave-max of per-lane radii; LDS padded +-256 with INF
// so no range checks. Per-thread only the needed polarity is scanned (the
// other field term is exactly 0 at every pixel).
__global__ __launch_bounds__(256) void k_row(
    const _Float16* __restrict__ err, const unsigned short* __restrict__ gAll,
    const int* __restrict__ cnts, float* __restrict__ partials)
{
    int h  = blockIdx.x;        // row 0..255
    int s  = blockIdx.y;        // slice 0..23
    int jo = threadIdx.x;

    __shared__ float4 g2[768];
    __shared__ float  wred[4];

    const size_t fstride = (size_t)NSL * HWTOT;
    size_t rbase = (size_t)s * HWTOT + h * WD + jo;

    int a  = gAll[rbase];                 // P
    int bb = gAll[fstride + rbase];       // Pc
    int c  = gAll[2 * fstride + rbase];   // T
    int dd = gAll[3 * fstride + rbase];   // Tc

    int cp = cnts[s];
    int ct = cnts[24 + s];
    bool validP = (cp > 0) && (cp < HWTOT);
    bool validT = (ct > 0) && (ct < HWTOT);
    bool selP = (a > 0);                  // pixel is True in maskP
    bool selT = (c > 0);

    int gsp = selP ? a : bb; if (!validP) gsp = 0;
    int gst = selT ? c : dd; if (!validT) gst = 0;

    float fa = (float)(a * a), fb = (float)(bb * bb);
    float fc = (float)(c * c), fd = (float)(dd * dd);
    g2[256 + jo] = make_float4(fa, fb, fc, fd);
    float4 inf4 = make_float4(1e30f, 1e30f, 1e30f, 1e30f);
    g2[jo] = inf4;
    g2[512 + jo] = inf4;

    int R = min(max(gsp, gst), 256);
    #pragma unroll
    for (int i = 1; i < 64; i <<= 1) R = max(R, __shfl_xor(R, i));

    float m1 = (float)(gsp * gsp);
    float m2 = (float)(gst * gst);
    __syncthreads();

    for (int d = 1; d < R; ++d) {
        float4 L = g2[256 + jo - d];
        float4 Rv = g2[256 + jo + d];
        float d2 = (float)(d * d);
        float c1 = fminf(selP ? L.x : L.y, selP ? Rv.x : Rv.y);
        float c2 = fminf(selT ? L.z : L.w, selT ? Rv.z : Rv.w);
        m1 = fminf(m1, c1 + d2);
        m2 = fminf(m2, c2 + d2);
    }

    float contrib = (float)err[rbase] * (m1 + m2);

    #pragma unroll
    for (int off = 32; off > 0; off >>= 1) contrib += __shfl_down(contrib, off);
    if ((jo & 63) == 0) wred[jo >> 6] = contrib;
    __syncthreads();
    if (jo == 0) partials[s * 256 + h] = wred[0] + wred[1] + wred[2] + wred[3];
}

// ---------------- Kernel 4: final reduce (double) + log ----------------
__global__ __launch_bounds__(256) void k_final(
    const float* __restrict__ partials, float* __restrict__ out)
{
    __shared__ double red[256];
    int t = threadIdx.x;
    double acc = 0.0;
    for (int i = t; i < NSL * 256; i += 256) acc += (double)partials[i];
    red[t] = acc;
    __syncthreads();
    for (int off = 128; off > 0; off >>= 1) {
        if (t < off) red[t] += red[t + off];
        __syncthreads();
    }
    if (t == 0) {
        double loss = red[0] / (double)((size_t)NSL * HWTOT);
        out[0] = (float)log(loss + 1.0);
    }
}

extern "C" void kernel_launch(void* const* d_in, const int* in_sizes, int n_in,
                              void* d_out, int out_size, void* d_ws, size_t ws_size,
                              hipStream_t stream)
{
    const float* pS = (const float*)d_in[0];
    const float* pT = (const float*)d_in[1];
    float* out = (float*)d_out;

    char* ws = (char*)d_ws;
    int*            cnts  = (int*)(ws + OFF_CNT);
    float*          parts = (float*)(ws + OFF_PART);
    unsigned char*  mask  = (unsigned char*)(ws + OFF_MASK);
    _Float16*       err   = (_Float16*)(ws + OFF_ERR);
    unsigned short* gAll  = (unsigned short*)(ws + OFF_G);

    hipMemsetAsync(ws, 0, HDR_BYTES, stream);

    k_mask <<<dim3(2048),     dim3(256), 0, stream>>>(pS, pT, mask, err, cnts);
    k_vert <<<dim3(NSL, 4),   dim3(256), 0, stream>>>(mask, gAll);
    k_row  <<<dim3(256, NSL), dim3(256), 0, stream>>>(err, gAll, cnts, parts);
    k_final<<<dim3(1),        dim3(256), 0, stream>>>(parts, out);
}

// Round 4
// 112.502 us; speedup vs baseline: 1.7210x; 1.1570x over previous
//
#include <hip/hip_runtime.h>
#include <math.h>

// Problem geometry (fixed): B=8, C=4, H=W=256; 24 = B*3 slices per mask type.
#define HWTOT 65536
#define WD 256
#define HT 256
#define NSL 24

// Workspace layout (bytes) — everything is written before read; no memset.
static constexpr size_t OFF_CNT  = 0;                         // 48 ints
static constexpr size_t OFF_PART = 256;                       // 6144 f32
static constexpr size_t OFF_PCNT = 24832;                     // 2*24*256 u16 = 24576
static constexpr size_t OFF_MASK = 49408;                     // 24*65536 u8 (bit0=P, bit1=T)
static constexpr size_t OFF_ERR  = OFF_MASK + (size_t)NSL * HWTOT;       // f16
static constexpr size_t OFF_G    = OFF_ERR + (size_t)NSL * HWTOT * 2;    // u16 x 2 fields
// gc fields: 0 = P, 1 = T; gc = column distance to nearest DIFFERING pixel
// (clamp 512). Reconstruction: gX = m ? gc : 0, gXc = m ? 0 : gc.

// ---------------- Kernel 1: masks + err + per-block counts ----------------
__global__ __launch_bounds__(256) void k_mask(
    const float* __restrict__ pS, const float* __restrict__ pT,
    unsigned char* __restrict__ mask, _Float16* __restrict__ err,
    unsigned short* __restrict__ pcnt)
{
    __shared__ int lc[6];
    if (threadIdx.x < 6) lc[threadIdx.x] = 0;
    __syncthreads();

    int blk = blockIdx.x;
    int b   = blk >> 8;          // image 0..7
    int lb  = blk & 255;         // block-within-image 0..255
    int hw  = lb * 256 + threadIdx.x;

    const float* ps = pS + (size_t)b * 4 * HWTOT + hw;
    float s0 = ps[0], s1 = ps[HWTOT], s2 = ps[2 * HWTOT], s3 = ps[3 * HWTOT];
    float mx = fmaxf(fmaxf(s0, s1), fmaxf(s2, s3));
    float e0 = expf(s0 - mx), e1 = expf(s1 - mx), e2 = expf(s2 - mx), e3 = expf(s3 - mx);
    float inv = 1.0f / (e0 + e1 + e2 + e3);

    const float* pt = pT + (size_t)b * 4 * HWTOT + hw;
    float t0 = pt[0], t1 = pt[HWTOT], t2 = pt[2 * HWTOT], t3 = pt[3 * HWTOT];
    int lab = 0; float bm = t0;
    if (t1 > bm) { bm = t1; lab = 1; }
    if (t2 > bm) { bm = t2; lab = 2; }
    if (t3 > bm) { bm = t3; lab = 3; }

    float pv[3] = { e1 * inv, e2 * inv, e3 * inv };
    #pragma unroll
    for (int cc = 0; cc < 3; ++cc) {
        int sl = b * 3 + cc;
        bool mp = pv[cc] > 0.5f;
        bool mt = (lab == cc + 1);
        mask[(size_t)sl * HWTOT + hw] = (unsigned char)((mp ? 1 : 0) | (mt ? 2 : 0));
        float tcv = mt ? 1.0f : 0.0f;
        float ev = (pv[cc] - tcv) * (pv[cc] - tcv);
        err[(size_t)sl * HWTOT + hw] = (_Float16)ev;
        unsigned long long balP = __ballot(mp);
        unsigned long long balT = __ballot(mt);
        if ((threadIdx.x & 63) == 0) {
            atomicAdd(&lc[cc],     (int)__popcll(balP));
            atomicAdd(&lc[3 + cc], (int)__popcll(balT));
        }
    }
    __syncthreads();
    if (threadIdx.x < 3) {
        int sl = b * 3 + threadIdx.x;
        pcnt[(size_t)sl * 256 + lb] = (unsigned short)lc[threadIdx.x];
    } else if (threadIdx.x < 6) {
        int sl = b * 3 + (threadIdx.x - 3);
        pcnt[(size_t)(NSL + sl) * 256 + lb] = (unsigned short)lc[threadIdx.x];
    }
}

// ---------------- Kernel 2: vertical pass (combined field) + count reduce ----
// Block = (slice s, masktype f). Thread = column. gc(h) = L1 distance within
// the column to the nearest row with a different mask bit, clamped at 512.
// Forward dist in registers (u16-packed), backward fused with min + store.
__global__ __launch_bounds__(256, 1) void k_vert(
    const unsigned char* __restrict__ mask, const unsigned short* __restrict__ pcnt,
    unsigned short* __restrict__ g, int* __restrict__ cnts)
{
    int s = blockIdx.x;          // slice 0..23
    int f = blockIdx.y;          // 0 = P (bit0), 1 = T (bit1)
    int w = threadIdx.x;

    const unsigned char* m = mask + (size_t)s * HWTOT + w;
    unsigned short* go = g + ((size_t)f * NSL + s) * HWTOT + w;

    unsigned up[128];            // packed forward distances (2 x u16)
    unsigned mb32[8];            // mask bit per row
    int prevm = -1, d = 512;
    #pragma unroll
    for (int hb = 0; hb < 16; ++hb) {
        unsigned char mraw[16];
        #pragma unroll
        for (int i = 0; i < 16; ++i) mraw[i] = m[(hb * 16 + i) * WD];
        #pragma unroll
        for (int i = 0; i < 16; ++i) {
            int h = hb * 16 + i;
            int mv = (mraw[i] >> f) & 1;
            d = (prevm < 0) ? 512 : ((mv != prevm) ? 1 : min(d + 1, 512));
            prevm = mv;
            if (h & 1) up[h >> 1] |= (unsigned)d << 16;
            else       up[h >> 1]  = (unsigned)d;
            if ((h & 31) == 0) mb32[h >> 5]  = (unsigned)mv;
            else               mb32[h >> 5] |= (unsigned)mv << (h & 31);
        }
    }
    int nextm = -1; d = 512;
    #pragma unroll
    for (int hb = 15; hb >= 0; --hb) {
        unsigned short outv[16];
        #pragma unroll
        for (int i = 15; i >= 0; --i) {
            int h = hb * 16 + i;
            int mv = (mb32[h >> 5] >> (h & 31)) & 1;
            d = (nextm < 0) ? 512 : ((mv != nextm) ? 1 : min(d + 1, 512));
            nextm = mv;
            unsigned pk = up[h >> 1];
            int du = (h & 1) ? (int)(pk >> 16) : (int)(pk & 0xffffu);
            outv[i] = (unsigned short)min(du, d);
        }
        #pragma unroll
        for (int i = 0; i < 16; ++i) go[(hb * 16 + i) * WD] = outv[i];
    }

    // Reduce this slice's per-block mask counts -> cnts (plain store, no init).
    __shared__ int cr[4];
    int v = (int)pcnt[((size_t)f * NSL + s) * 256 + w];
    #pragma unroll
    for (int i = 1; i < 64; i <<= 1) v += __shfl_xor(v, i);
    if ((w & 63) == 0) cr[w >> 6] = v;
    __syncthreads();
    if (w == 0) cnts[f * NSL + s] = cr[0] + cr[1] + cr[2] + cr[3];
}

// ---------------- Kernel 3: horizontal min, radius-limited, fused loss ------
__global__ __launch_bounds__(256) void k_row(
    const _Float16* __restrict__ err, const unsigned short* __restrict__ gAll,
    const unsigned char* __restrict__ mask,
    const int* __restrict__ cnts, float* __restrict__ partials)
{
    int h  = blockIdx.x;        // row 0..255
    int s  = blockIdx.y;        // slice 0..23
    int jo = threadIdx.x;

    __shared__ float4 g2[768];
    __shared__ float  wred[4];

    const size_t fstride = (size_t)NSL * HWTOT;
    size_t rbase = (size_t)s * HWTOT + h * WD + jo;

    int gcP = gAll[rbase];
    int gcT = gAll[fstride + rbase];
    int mb  = mask[rbase];
    bool selP = mb & 1;
    bool selT = (mb >> 1) & 1;

    int cp = cnts[s];
    int ct = cnts[NSL + s];
    bool validP = (cp > 0) && (cp < HWTOT);
    bool validT = (ct > 0) && (ct < HWTOT);

    float fP = (float)(gcP * gcP);
    float fT = (float)(gcT * gcT);
    g2[256 + jo] = make_float4(selP ? fP : 0.0f, selP ? 0.0f : fP,
                               selT ? fT : 0.0f, selT ? 0.0f : fT);
    float4 inf4 = make_float4(1e30f, 1e30f, 1e30f, 1e30f);
    g2[jo] = inf4;
    g2[512 + jo] = inf4;

    int gsp = validP ? gcP : 0;
    int gst = validT ? gcT : 0;
    int R = min(max(gsp, gst), 256);
    #pragma unroll
    for (int i = 1; i < 64; i <<= 1) R = max(R, __shfl_xor(R, i));

    float m1 = (float)(gsp * gsp);
    float m2 = (float)(gst * gst);
    __syncthreads();

    for (int dd = 1; dd < R; ++dd) {
        float4 L  = g2[256 + jo - dd];
        float4 Rv = g2[256 + jo + dd];
        float d2 = (float)(dd * dd);
        float c1 = fminf(selP ? L.x : L.y, selP ? Rv.x : Rv.y);
        float c2 = fminf(selT ? L.z : L.w, selT ? Rv.z : Rv.w);
        m1 = fminf(m1, c1 + d2);
        m2 = fminf(m2, c2 + d2);
    }

    float contrib = (float)err[rbase] * (m1 + m2);

    #pragma unroll
    for (int off = 32; off > 0; off >>= 1) contrib += __shfl_down(contrib, off);
    if ((jo & 63) == 0) wred[jo >> 6] = contrib;
    __syncthreads();
    if (jo == 0) partials[s * 256 + h] = wred[0] + wred[1] + wred[2] + wred[3];
}

// ---------------- Kernel 4: final reduce (double) + log ----------------
__global__ __launch_bounds__(256) void k_final(
    const float* __restrict__ partials, float* __restrict__ out)
{
    __shared__ double red[256];
    int t = threadIdx.x;
    double acc = 0.0;
    for (int i = t; i < NSL * 256; i += 256) acc += (double)partials[i];
    red[t] = acc;
    __syncthreads();
    for (int off = 128; off > 0; off >>= 1) {
        if (t < off) red[t] += red[t + off];
        __syncthreads();
    }
    if (t == 0) {
        double loss = red[0] / (double)((size_t)NSL * HWTOT);
        out[0] = (float)log(loss + 1.0);
    }
}

extern "C" void kernel_launch(void* const* d_in, const int* in_sizes, int n_in,
                              void* d_out, int out_size, void* d_ws, size_t ws_size,
                              hipStream_t stream)
{
    const float* pS = (const float*)d_in[0];
    const float* pT = (const float*)d_in[1];
    float* out = (float*)d_out;

    char* ws = (char*)d_ws;
    int*            cnts  = (int*)(ws + OFF_CNT);
    float*          parts = (float*)(ws + OFF_PART);
    unsigned short* pcnt  = (unsigned short*)(ws + OFF_PCNT);
    unsigned char*  mask  = (unsigned char*)(ws + OFF_MASK);
    _Float16*       err   = (_Float16*)(ws + OFF_ERR);
    unsigned short* gAll  = (unsigned short*)(ws + OFF_G);

    k_mask <<<dim3(2048),     dim3(256), 0, stream>>>(pS, pT, mask, err, pcnt);
    k_vert <<<dim3(NSL, 2),   dim3(256), 0, stream>>>(mask, pcnt, gAll, cnts);
    k_row  <<<dim3(256, NSL), dim3(256), 0, stream>>>(err, gAll, mask, cnts, parts);
    k_final<<<dim3(1),        dim3(256), 0, stream>>>(parts, out);
}